// Round 8
// baseline (55.549 us; speedup 1.0000x reference)
//
#include <hip/hip_runtime.h>
#include <hip/hip_bf16.h>
#include <cstdint>

#define B_ 16
#define T_ 4096
#define D_ 1024
#define E_ 64
#define THRESH 1.0f
#define MBLK 128      // timesteps per block (4 waves x 32 rows)
#define BK 32         // k per chunk
#define NCH 32        // D_/BK

typedef float f32x4 __attribute__((ext_vector_type(4)));
typedef short s16x8 __attribute__((ext_vector_type(8)));

typedef __attribute__((address_space(3))) void lds_void_t;
typedef const __attribute__((address_space(1))) void gbl_void_t;

// fp32 -> bf16 hi/lo split: v = hi + lo + O(2^-17 * v)
__device__ __forceinline__ void split1(float v, unsigned short& h, unsigned short& l) {
    unsigned u = __float_as_uint(v);
    float hf = __uint_as_float(u & 0xFFFF0000u);
    float r = v - hf;
    h = (unsigned short)(u >> 16);
    l = (unsigned short)(__float_as_uint(r) >> 16);
}

__device__ __forceinline__ void split8(float4 v0, float4 v1, s16x8& h8, s16x8& l8) {
    unsigned short h0,h1,h2,h3,h4,h5,h6,h7, l0,l1,l2,l3,l4,l5,l6,l7;
    split1(v0.x,h0,l0); split1(v0.y,h1,l1); split1(v0.z,h2,l2); split1(v0.w,h3,l3);
    split1(v1.x,h4,l4); split1(v1.y,h5,l5); split1(v1.z,h6,l6); split1(v1.w,h7,l7);
    h8 = (s16x8){(short)h0,(short)h1,(short)h2,(short)h3,(short)h4,(short)h5,(short)h6,(short)h7};
    l8 = (s16x8){(short)l0,(short)l1,(short)l2,(short)l3,(short)l4,(short)l5,(short)l6,(short)l7};
}

// XOR swizzle within a 128-byte row (involution, both-sides applied)
__device__ __forceinline__ int swz128(int row, int cb) {
    return cb ^ ((row & 3) << 5) ^ (((row >> 2) & 1) << 4);
}

// ---------------- kernel 1: depth-3 counted-vmcnt pipelined GEMM ----------------
// grid = 512 (B*T/128), 256 threads (4 waves). Three stages in flight
// (vmcnt(12) steady state): each chunk's loads get ~2 compute phases of
// latency coverage instead of 1. LDS 72 KB = 3 x (16K A + 8K W), 2 blocks/CU.
__global__ __launch_bounds__(256, 2) void lif_gemm_kernel(
    const float* __restrict__ seq, const float* __restrict__ Wg,
    const float* __restrict__ bias, const float* __restrict__ beta_raw,
    float* __restrict__ Cw, float* __restrict__ Mw)
{
    __shared__ __align__(16) unsigned char lds[73728];
    unsigned char* const A0 = lds;               // 16384 each: A fp32 [128][128B]
    unsigned char* const A1 = lds + 16384;
    unsigned char* const A2 = lds + 32768;
    unsigned char* const W0 = lds + 49152;       // 8192 each: W fp32 [64][128B]
    unsigned char* const W1 = lds + 57344;
    unsigned char* const W2 = lds + 65536;

    const int tid  = threadIdx.x;
    const int wave = tid >> 6;
    const int lane = tid & 63;
    const int c = lane & 15;
    const int q = lane >> 4;
    const long row0 = (long)blockIdx.x * MBLK;

    // stage one k-chunk: 6 global_load_lds per thread (4 A + 2 W), all fp32
    auto stage = [&](unsigned char* Ab, unsigned char* Wb, int k0) {
        #pragma unroll
        for (int i = 0; i < 4; ++i) {
            int o16 = i * 256 + wave * 64 + lane;
            int row = o16 >> 3;                  // 0..127
            int cb  = (o16 & 7) << 4;
            int cbs = swz128(row, cb);
            gbl_void_t* src = (gbl_void_t*)(seq + (row0 + row) * D_ + k0 + (cbs >> 2));
            lds_void_t* dst = (lds_void_t*)(Ab + (i * 256 + wave * 64) * 16);
            __builtin_amdgcn_global_load_lds(src, dst, 16, 0, 0);
        }
        #pragma unroll
        for (int i = 0; i < 2; ++i) {
            int o16 = i * 256 + wave * 64 + lane;
            int row = o16 >> 3;                  // 0..63
            int cb  = (o16 & 7) << 4;
            int cbs = swz128(row, cb);
            gbl_void_t* src = (gbl_void_t*)(Wg + row * D_ + k0 + (cbs >> 2));
            lds_void_t* dst = (lds_void_t*)(Wb + (i * 256 + wave * 64) * 16);
            __builtin_amdgcn_global_load_lds(src, dst, 16, 0, 0);
        }
    };

    f32x4 acc[2][4] = {};

    auto compute = [&](const unsigned char* Ab, const unsigned char* Wb) {
        s16x8 ah[2], al[2], bh[4], bl[4];
        #pragma unroll
        for (int m = 0; m < 2; ++m) {
            int r = wave * 32 + m * 16 + c;
            float4 v0 = *(const float4*)(Ab + r * 128 + swz128(r, q * 32));
            float4 v1 = *(const float4*)(Ab + r * 128 + swz128(r, q * 32 + 16));
            split8(v0, v1, ah[m], al[m]);
        }
        #pragma unroll
        for (int n = 0; n < 4; ++n) {
            int r = n * 16 + c;
            float4 w0 = *(const float4*)(Wb + r * 128 + swz128(r, q * 32));
            float4 w1 = *(const float4*)(Wb + r * 128 + swz128(r, q * 32 + 16));
            split8(w0, w1, bh[n], bl[n]);
        }
        #pragma unroll
        for (int m = 0; m < 2; ++m)
            #pragma unroll
            for (int n = 0; n < 4; ++n)
                acc[m][n] = __builtin_amdgcn_mfma_f32_16x16x32_bf16(ah[m], bh[n], acc[m][n], 0, 0, 0);
        #pragma unroll
        for (int m = 0; m < 2; ++m)
            #pragma unroll
            for (int n = 0; n < 4; ++n)
                acc[m][n] = __builtin_amdgcn_mfma_f32_16x16x32_bf16(al[m], bh[n], acc[m][n], 0, 0, 0);
        #pragma unroll
        for (int m = 0; m < 2; ++m)
            #pragma unroll
            for (int n = 0; n < 4; ++n)
                acc[m][n] = __builtin_amdgcn_mfma_f32_16x16x32_bf16(ah[m], bl[n], acc[m][n], 0, 0, 0);
    };

    // ---- prologue: three stages in flight (18 loads) ----
    stage(A0, W0, 0);
    stage(A1, W1, BK);
    stage(A2, W2, 2 * BK);

    // ---- main loop: chunks 0..26, staging up to chunk 29; vmcnt(12) steady ----
    for (int t = 0; t < 27; t += 3) {
        asm volatile("s_waitcnt vmcnt(12)" ::: "memory");  // chunk t landed; t+1,t+2 in flight
        __builtin_amdgcn_s_barrier();
        compute(A0, W0);
        asm volatile("s_waitcnt lgkmcnt(0)" ::: "memory");
        __builtin_amdgcn_s_barrier();
        stage(A0, W0, (t + 3) * BK);

        asm volatile("s_waitcnt vmcnt(12)" ::: "memory");
        __builtin_amdgcn_s_barrier();
        compute(A1, W1);
        asm volatile("s_waitcnt lgkmcnt(0)" ::: "memory");
        __builtin_amdgcn_s_barrier();
        stage(A1, W1, (t + 4) * BK);

        asm volatile("s_waitcnt vmcnt(12)" ::: "memory");
        __builtin_amdgcn_s_barrier();
        compute(A2, W2);
        asm volatile("s_waitcnt lgkmcnt(0)" ::: "memory");
        __builtin_amdgcn_s_barrier();
        stage(A2, W2, (t + 5) * BK);
    }
    // ---- tail: chunks 27..31 ----
    asm volatile("s_waitcnt vmcnt(12)" ::: "memory");      // 27 landed; 28,29 in flight
    __builtin_amdgcn_s_barrier();
    compute(A0, W0);
    asm volatile("s_waitcnt lgkmcnt(0)" ::: "memory");
    __builtin_amdgcn_s_barrier();
    stage(A0, W0, 30 * BK);

    asm volatile("s_waitcnt vmcnt(12)" ::: "memory");      // 28 landed; 29,30 in flight
    __builtin_amdgcn_s_barrier();
    compute(A1, W1);
    asm volatile("s_waitcnt lgkmcnt(0)" ::: "memory");
    __builtin_amdgcn_s_barrier();
    stage(A1, W1, 31 * BK);

    asm volatile("s_waitcnt vmcnt(12)" ::: "memory");      // 29 landed; 30,31 in flight
    __builtin_amdgcn_s_barrier();
    compute(A2, W2);

    asm volatile("s_waitcnt vmcnt(6)" ::: "memory");       // 30 landed; 31 in flight
    __builtin_amdgcn_s_barrier();
    compute(A0, W0);

    asm volatile("s_waitcnt vmcnt(0)" ::: "memory");       // 31 landed
    __builtin_amdgcn_s_barrier();
    compute(A1, W1);

    // ---- epilogue: in-register scan compose, f(U)=min(beta*U + I_t, 1) ----
    // C/D layout: col = c (=> e = n*16+c), row = q*4 + r (=> t offset = m*16 + q*4 + r)
    float beta[4], A4[4], A8[4], bi[4];
    #pragma unroll
    for (int n = 0; n < 4; ++n) {
        beta[n] = 1.0f / (1.0f + __expf(-beta_raw[n * 16 + c]));
        float b2 = beta[n] * beta[n];
        A4[n] = b2 * b2;
        A8[n] = A4[n] * A4[n];
        bi[n] = bias[n * 16 + c];
    }

    float C[2][4], M[2][4];
    #pragma unroll
    for (int m = 0; m < 2; ++m)
        #pragma unroll
        for (int n = 0; n < 4; ++n) {
            float Cc = 0.0f, Mm = 3.0e38f;
            #pragma unroll
            for (int r = 0; r < 4; ++r) {
                float v = acc[m][n][r] + bi[n];
                Cc = fmaf(beta[n], Cc, v);
                Mm = fminf(fmaf(beta[n], Mm, v), THRESH);
            }
            C[m][n] = Cc; M[m][n] = Mm;
        }

    #pragma unroll
    for (int m = 0; m < 2; ++m)
        #pragma unroll
        for (int n = 0; n < 4; ++n) {
            {   // seglen 4 -> 8, A2 = beta^4
                float Cp = __shfl_xor(C[m][n], 16, 64);
                float Mp = __shfl_xor(M[m][n], 16, 64);
                bool sf = (lane & 16) == 0;
                float Cf = sf ? C[m][n] : Cp, Cs = sf ? Cp : C[m][n];
                float Mf = sf ? M[m][n] : Mp, Ms = sf ? Mp : M[m][n];
                C[m][n] = fmaf(A4[n], Cf, Cs);
                M[m][n] = fminf(fmaf(A4[n], Mf, Cs), Ms);
            }
            {   // seglen 8 -> 16, A2 = beta^8
                float Cp = __shfl_xor(C[m][n], 32, 64);
                float Mp = __shfl_xor(M[m][n], 32, 64);
                bool sf = (lane & 32) == 0;
                float Cf = sf ? C[m][n] : Cp, Cs = sf ? Cp : C[m][n];
                float Mf = sf ? M[m][n] : Mp, Ms = sf ? Mp : M[m][n];
                C[m][n] = fmaf(A8[n], Cf, Cs);
                M[m][n] = fminf(fmaf(A8[n], Mf, Cs), Ms);
            }
        }

    float Cm[4], Mm4[4];
    #pragma unroll
    for (int n = 0; n < 4; ++n) {
        float A16 = A8[n] * A8[n];
        Cm[n]  = fmaf(A16, C[0][n], C[1][n]);
        Mm4[n] = fminf(fmaf(A16, M[0][n], C[1][n]), M[1][n]);
    }

    float Co = (q == 0) ? Cm[0] : (q == 1) ? Cm[1] : (q == 2) ? Cm[2] : Cm[3];
    float Mo = (q == 0) ? Mm4[0] : (q == 1) ? Mm4[1] : (q == 2) ? Mm4[2] : Mm4[3];
    int sub = blockIdx.x * 4 + wave;
    Cw[sub * 64 + q * 16 + c] = Co;
    Mw[sub * 64 + q * 16 + c] = Mo;
}

// ---------------- kernel 2: combine 128 sub-chunks per batch + softmax ----------------
__global__ void lif_combine_kernel(const float* __restrict__ Cw, const float* __restrict__ Mw,
                                   const float* __restrict__ beta_raw, float* __restrict__ out)
{
    __shared__ float Cs[4][64], Ms[4][64];
    const int b = blockIdx.x;
    const int wv = threadIdx.x >> 6;
    const int e  = threadIdx.x & 63;

    float beta = 1.0f / (1.0f + __expf(-beta_raw[e]));
    float A32 = beta * beta;   // ^2
    A32 = A32 * A32;           // ^4
    A32 = A32 * A32;           // ^8
    A32 = A32 * A32;           // ^16
    A32 = A32 * A32;           // ^32

    const float* Cp = Cw + ((size_t)b * 128 + wv * 32) * 64 + e;
    const float* Mp = Mw + ((size_t)b * 128 + wv * 32) * 64 + e;
    float Cc = Cp[0], Mm = Mp[0];
    #pragma unroll 8
    for (int i = 1; i < 32; ++i) {
        float ci = Cp[i * 64], mi = Mp[i * 64];
        Mm = fminf(fmaf(A32, Mm, ci), mi);
        Cc = fmaf(A32, Cc, ci);
    }
    Cs[wv][e] = Cc; Ms[wv][e] = Mm;
    __syncthreads();

    if (threadIdx.x < 64) {
        float Ag = A32;            // -> beta^1024 via 5 squarings
        Ag = Ag * Ag; Ag = Ag * Ag; Ag = Ag * Ag; Ag = Ag * Ag; Ag = Ag * Ag;
        float C0 = Cs[0][e], M0 = Ms[0][e];
        #pragma unroll
        for (int g = 1; g < 4; ++g) {
            float ci = Cs[g][e], mi = Ms[g][e];
            M0 = fminf(fmaf(Ag, M0, ci), mi);
            C0 = fmaf(Ag, C0, ci);
        }
        float U = fminf(C0, M0);
        float m = U;
        #pragma unroll
        for (int off = 32; off; off >>= 1) m = fmaxf(m, __shfl_xor(m, off, 64));
        float ex = __expf(U - m);
        float s = ex;
        #pragma unroll
        for (int off = 32; off; off >>= 1) s += __shfl_xor(s, off, 64);
        out[b * 64 + e] = ex / s;
    }
}

extern "C" void kernel_launch(void* const* d_in, const int* in_sizes, int n_in,
                              void* d_out, int out_size, void* d_ws, size_t ws_size,
                              hipStream_t stream)
{
    const float* seq  = (const float*)d_in[0];
    const float* W    = (const float*)d_in[1];
    const float* bias = (const float*)d_in[2];
    const float* braw = (const float*)d_in[3];
    float* out = (float*)d_out;

    char* ws = (char*)d_ws;
    float* Cw = (float*)ws;                     // 2048*64*4 = 524288 B
    float* Mw = (float*)(ws + 524288);          // 524288 B

    lif_gemm_kernel<<<(B_ * T_) / MBLK, 256, 0, stream>>>(seq, W, bias, braw, Cw, Mw);
    lif_combine_kernel<<<B_, 256, 0, stream>>>(Cw, Mw, braw, out);
}

// Round 9
// 54.127 us; speedup vs baseline: 1.0263x; 1.0263x over previous
//
#include <hip/hip_runtime.h>
#include <hip/hip_bf16.h>
#include <cstdint>

#define B_ 16
#define T_ 4096
#define D_ 1024
#define E_ 64
#define THRESH 1.0f
#define MBLK 64       // timesteps per block (2 waves x 32 rows)
#define BK 32         // k per chunk
#define NCH 32        // D_/BK

typedef float f32x4 __attribute__((ext_vector_type(4)));
typedef short s16x8 __attribute__((ext_vector_type(8)));

typedef __attribute__((address_space(3))) void lds_void_t;
typedef const __attribute__((address_space(1))) void gbl_void_t;

// fp32 -> bf16 hi/lo split: v = hi + lo + O(2^-17 * v)
__device__ __forceinline__ void split1(float v, unsigned short& h, unsigned short& l) {
    unsigned u = __float_as_uint(v);
    float hf = __uint_as_float(u & 0xFFFF0000u);
    float r = v - hf;
    h = (unsigned short)(u >> 16);
    l = (unsigned short)(__float_as_uint(r) >> 16);
}

__device__ __forceinline__ void split8(float4 v0, float4 v1, s16x8& h8, s16x8& l8) {
    unsigned short h0,h1,h2,h3,h4,h5,h6,h7, l0,l1,l2,l3,l4,l5,l6,l7;
    split1(v0.x,h0,l0); split1(v0.y,h1,l1); split1(v0.z,h2,l2); split1(v0.w,h3,l3);
    split1(v1.x,h4,l4); split1(v1.y,h5,l5); split1(v1.z,h6,l6); split1(v1.w,h7,l7);
    h8 = (s16x8){(short)h0,(short)h1,(short)h2,(short)h3,(short)h4,(short)h5,(short)h6,(short)h7};
    l8 = (s16x8){(short)l0,(short)l1,(short)l2,(short)l3,(short)l4,(short)l5,(short)l6,(short)l7};
}

// XOR swizzle within a 128-byte row (involution, both-sides applied)
__device__ __forceinline__ int swz128(int row, int cb) {
    return cb ^ ((row & 3) << 5) ^ (((row >> 2) & 1) << 4);
}

// ---------------- kernel 1: depth-2 pipelined GEMM, 2-wave blocks ----------------
// grid = 1024 (B*T/64), 128 threads (2 waves). Round-7 pipeline discipline;
// 4 independent blocks/CU (32KB LDS each) -> 4 staging streams per CU.
__global__ __launch_bounds__(128, 2) void lif_gemm_kernel(
    const float* __restrict__ seq, const float* __restrict__ Wg,
    const float* __restrict__ bias, const float* __restrict__ beta_raw,
    float* __restrict__ Cw, float* __restrict__ Mw)
{
    __shared__ __align__(16) unsigned char lds[32768];
    unsigned char* const A0 = lds;               // 8192: A fp32 [64][128B]
    unsigned char* const A1 = lds + 8192;        // 8192
    unsigned char* const W0 = lds + 16384;       // 8192: W fp32 [64][128B]
    unsigned char* const W1 = lds + 24576;       // 8192

    const int tid  = threadIdx.x;
    const int wave = tid >> 6;                   // 0..1
    const int lane = tid & 63;
    const int c = lane & 15;
    const int q = lane >> 4;
    const long row0 = (long)blockIdx.x * MBLK;

    // stage one k-chunk: 8 global_load_lds per thread (4 A + 4 W), all fp32
    auto stage = [&](unsigned char* Ab, unsigned char* Wb, int k0) {
        #pragma unroll
        for (int i = 0; i < 4; ++i) {
            int o16 = i * 128 + tid;             // 512 16B-units = 64 rows x 128B
            int row = o16 >> 3;                  // 0..63
            int cb  = (o16 & 7) << 4;
            int cbs = swz128(row, cb);
            gbl_void_t* src = (gbl_void_t*)(seq + (row0 + row) * D_ + k0 + (cbs >> 2));
            lds_void_t* dst = (lds_void_t*)(Ab + o16 * 16);
            __builtin_amdgcn_global_load_lds(src, dst, 16, 0, 0);
        }
        #pragma unroll
        for (int i = 0; i < 4; ++i) {
            int o16 = i * 128 + tid;
            int row = o16 >> 3;                  // 0..63
            int cb  = (o16 & 7) << 4;
            int cbs = swz128(row, cb);
            gbl_void_t* src = (gbl_void_t*)(Wg + row * D_ + k0 + (cbs >> 2));
            lds_void_t* dst = (lds_void_t*)(Wb + o16 * 16);
            __builtin_amdgcn_global_load_lds(src, dst, 16, 0, 0);
        }
    };

    f32x4 acc[2][4] = {};

    auto compute = [&](const unsigned char* Ab, const unsigned char* Wb) {
        s16x8 ah[2], al[2], bh[4], bl[4];
        #pragma unroll
        for (int m = 0; m < 2; ++m) {
            int r = wave * 32 + m * 16 + c;      // 0..63
            float4 v0 = *(const float4*)(Ab + r * 128 + swz128(r, q * 32));
            float4 v1 = *(const float4*)(Ab + r * 128 + swz128(r, q * 32 + 16));
            split8(v0, v1, ah[m], al[m]);
        }
        #pragma unroll
        for (int n = 0; n < 4; ++n) {
            int r = n * 16 + c;
            float4 w0 = *(const float4*)(Wb + r * 128 + swz128(r, q * 32));
            float4 w1 = *(const float4*)(Wb + r * 128 + swz128(r, q * 32 + 16));
            split8(w0, w1, bh[n], bl[n]);
        }
        #pragma unroll
        for (int m = 0; m < 2; ++m)
            #pragma unroll
            for (int n = 0; n < 4; ++n)
                acc[m][n] = __builtin_amdgcn_mfma_f32_16x16x32_bf16(ah[m], bh[n], acc[m][n], 0, 0, 0);
        #pragma unroll
        for (int m = 0; m < 2; ++m)
            #pragma unroll
            for (int n = 0; n < 4; ++n)
                acc[m][n] = __builtin_amdgcn_mfma_f32_16x16x32_bf16(al[m], bh[n], acc[m][n], 0, 0, 0);
        #pragma unroll
        for (int m = 0; m < 2; ++m)
            #pragma unroll
            for (int n = 0; n < 4; ++n)
                acc[m][n] = __builtin_amdgcn_mfma_f32_16x16x32_bf16(ah[m], bl[n], acc[m][n], 0, 0, 0);
    };

    // ---- prologue: two stages in flight (16 loads) ----
    stage(A0, W0, 0);
    stage(A1, W1, BK);

    // ---- main loop: never drain vmcnt to 0 ----
    for (int t = 0; t < NCH - 2; t += 2) {
        asm volatile("s_waitcnt vmcnt(8)" ::: "memory");   // chunk t landed; t+1 in flight
        __builtin_amdgcn_s_barrier();
        compute(A0, W0);
        asm volatile("s_waitcnt lgkmcnt(0)" ::: "memory");
        __builtin_amdgcn_s_barrier();                       // all waves done reading buf0
        stage(A0, W0, (t + 2) * BK);

        asm volatile("s_waitcnt vmcnt(8)" ::: "memory");
        __builtin_amdgcn_s_barrier();
        compute(A1, W1);
        asm volatile("s_waitcnt lgkmcnt(0)" ::: "memory");
        __builtin_amdgcn_s_barrier();
        stage(A1, W1, (t + 3) * BK);
    }
    asm volatile("s_waitcnt vmcnt(8)" ::: "memory");
    __builtin_amdgcn_s_barrier();
    compute(A0, W0);
    asm volatile("s_waitcnt lgkmcnt(0)" ::: "memory");
    __builtin_amdgcn_s_barrier();
    asm volatile("s_waitcnt vmcnt(0)" ::: "memory");       // final drain
    __builtin_amdgcn_s_barrier();
    compute(A1, W1);

    // ---- epilogue: in-register scan compose, f(U)=min(beta*U + I_t, 1) ----
    // C/D layout: col = c (=> e = n*16+c), row = q*4 + r (=> t offset = m*16 + q*4 + r)
    float beta[4], A4[4], A8[4], bi[4];
    #pragma unroll
    for (int n = 0; n < 4; ++n) {
        beta[n] = 1.0f / (1.0f + __expf(-beta_raw[n * 16 + c]));
        float b2 = beta[n] * beta[n];
        A4[n] = b2 * b2;
        A8[n] = A4[n] * A4[n];
        bi[n] = bias[n * 16 + c];
    }

    float C[2][4], M[2][4];
    #pragma unroll
    for (int m = 0; m < 2; ++m)
        #pragma unroll
        for (int n = 0; n < 4; ++n) {
            float Cc = 0.0f, Mm = 3.0e38f;
            #pragma unroll
            for (int r = 0; r < 4; ++r) {
                float v = acc[m][n][r] + bi[n];
                Cc = fmaf(beta[n], Cc, v);
                Mm = fminf(fmaf(beta[n], Mm, v), THRESH);
            }
            C[m][n] = Cc; M[m][n] = Mm;
        }

    #pragma unroll
    for (int m = 0; m < 2; ++m)
        #pragma unroll
        for (int n = 0; n < 4; ++n) {
            {   // seglen 4 -> 8, A2 = beta^4
                float Cp = __shfl_xor(C[m][n], 16, 64);
                float Mp = __shfl_xor(M[m][n], 16, 64);
                bool sf = (lane & 16) == 0;
                float Cf = sf ? C[m][n] : Cp, Cs = sf ? Cp : C[m][n];
                float Mf = sf ? M[m][n] : Mp, Ms = sf ? Mp : M[m][n];
                C[m][n] = fmaf(A4[n], Cf, Cs);
                M[m][n] = fminf(fmaf(A4[n], Mf, Cs), Ms);
            }
            {   // seglen 8 -> 16, A2 = beta^8
                float Cp = __shfl_xor(C[m][n], 32, 64);
                float Mp = __shfl_xor(M[m][n], 32, 64);
                bool sf = (lane & 32) == 0;
                float Cf = sf ? C[m][n] : Cp, Cs = sf ? Cp : C[m][n];
                float Mf = sf ? M[m][n] : Mp, Ms = sf ? Mp : M[m][n];
                C[m][n] = fmaf(A8[n], Cf, Cs);
                M[m][n] = fminf(fmaf(A8[n], Mf, Cs), Ms);
            }
        }

    float Cm[4], Mm4[4];
    #pragma unroll
    for (int n = 0; n < 4; ++n) {
        float A16 = A8[n] * A8[n];
        Cm[n]  = fmaf(A16, C[0][n], C[1][n]);
        Mm4[n] = fminf(fmaf(A16, M[0][n], C[1][n]), M[1][n]);
    }

    float Co = (q == 0) ? Cm[0] : (q == 1) ? Cm[1] : (q == 2) ? Cm[2] : Cm[3];
    float Mo = (q == 0) ? Mm4[0] : (q == 1) ? Mm4[1] : (q == 2) ? Mm4[2] : Mm4[3];
    int sub = blockIdx.x * 2 + wave;             // t-order preserved: sub covers [sub*32, sub*32+32)
    Cw[sub * 64 + q * 16 + c] = Co;
    Mw[sub * 64 + q * 16 + c] = Mo;
}

// ---------------- kernel 2: combine 128 sub-chunks per batch + softmax ----------------
__global__ void lif_combine_kernel(const float* __restrict__ Cw, const float* __restrict__ Mw,
                                   const float* __restrict__ beta_raw, float* __restrict__ out)
{
    __shared__ float Cs[4][64], Ms[4][64];
    const int b = blockIdx.x;
    const int wv = threadIdx.x >> 6;
    const int e  = threadIdx.x & 63;

    float beta = 1.0f / (1.0f + __expf(-beta_raw[e]));
    float A32 = beta * beta;   // ^2
    A32 = A32 * A32;           // ^4
    A32 = A32 * A32;           // ^8
    A32 = A32 * A32;           // ^16
    A32 = A32 * A32;           // ^32

    const float* Cp = Cw + ((size_t)b * 128 + wv * 32) * 64 + e;
    const float* Mp = Mw + ((size_t)b * 128 + wv * 32) * 64 + e;
    float Cc = Cp[0], Mm = Mp[0];
    #pragma unroll 8
    for (int i = 1; i < 32; ++i) {
        float ci = Cp[i * 64], mi = Mp[i * 64];
        Mm = fminf(fmaf(A32, Mm, ci), mi);
        Cc = fmaf(A32, Cc, ci);
    }
    Cs[wv][e] = Cc; Ms[wv][e] = Mm;
    __syncthreads();

    if (threadIdx.x < 64) {
        float Ag = A32;            // -> beta^1024 via 5 squarings
        Ag = Ag * Ag; Ag = Ag * Ag; Ag = Ag * Ag; Ag = Ag * Ag; Ag = Ag * Ag;
        float C0 = Cs[0][e], M0 = Ms[0][e];
        #pragma unroll
        for (int g = 1; g < 4; ++g) {
            float ci = Cs[g][e], mi = Ms[g][e];
            M0 = fminf(fmaf(Ag, M0, ci), mi);
            C0 = fmaf(Ag, C0, ci);
        }
        float U = fminf(C0, M0);
        float m = U;
        #pragma unroll
        for (int off = 32; off; off >>= 1) m = fmaxf(m, __shfl_xor(m, off, 64));
        float ex = __expf(U - m);
        float s = ex;
        #pragma unroll
        for (int off = 32; off; off >>= 1) s += __shfl_xor(s, off, 64);
        out[b * 64 + e] = ex / s;
    }
}

extern "C" void kernel_launch(void* const* d_in, const int* in_sizes, int n_in,
                              void* d_out, int out_size, void* d_ws, size_t ws_size,
                              hipStream_t stream)
{
    const float* seq  = (const float*)d_in[0];
    const float* W    = (const float*)d_in[1];
    const float* bias = (const float*)d_in[2];
    const float* braw = (const float*)d_in[3];
    float* out = (float*)d_out;

    char* ws = (char*)d_ws;
    float* Cw = (float*)ws;                     // 2048*64*4 = 524288 B
    float* Mw = (float*)(ws + 524288);          // 524288 B

    lif_gemm_kernel<<<(B_ * T_) / MBLK, 128, 0, stream>>>(seq, W, bias, braw, Cw, Mw);
    lif_combine_kernel<<<B_, 256, 0, stream>>>(Cw, Mw, braw, out);
}

// Round 10
// 51.890 us; speedup vs baseline: 1.0705x; 1.0431x over previous
//
#include <hip/hip_runtime.h>
#include <hip/hip_bf16.h>
#include <cstdint>

#define B_ 16
#define T_ 4096
#define D_ 1024
#define E_ 64
#define THRESH 1.0f
#define MBLK 128      // timesteps per block (4 waves x 32 rows)
#define BK 32         // k per chunk
#define NCH 32        // D_/BK

typedef float f32x4 __attribute__((ext_vector_type(4)));
typedef short s16x8 __attribute__((ext_vector_type(8)));

typedef __attribute__((address_space(3))) void lds_void_t;
typedef const __attribute__((address_space(1))) void gbl_void_t;

// fp32 -> bf16 hi/lo split: v = hi + lo + O(2^-17 * v)
__device__ __forceinline__ void split1(float v, unsigned short& h, unsigned short& l) {
    unsigned u = __float_as_uint(v);
    float hf = __uint_as_float(u & 0xFFFF0000u);
    float r = v - hf;
    h = (unsigned short)(u >> 16);
    l = (unsigned short)(__float_as_uint(r) >> 16);
}

__device__ __forceinline__ void split8(float4 v0, float4 v1, s16x8& h8, s16x8& l8) {
    unsigned short h0,h1,h2,h3,h4,h5,h6,h7, l0,l1,l2,l3,l4,l5,l6,l7;
    split1(v0.x,h0,l0); split1(v0.y,h1,l1); split1(v0.z,h2,l2); split1(v0.w,h3,l3);
    split1(v1.x,h4,l4); split1(v1.y,h5,l5); split1(v1.z,h6,l6); split1(v1.w,h7,l7);
    h8 = (s16x8){(short)h0,(short)h1,(short)h2,(short)h3,(short)h4,(short)h5,(short)h6,(short)h7};
    l8 = (s16x8){(short)l0,(short)l1,(short)l2,(short)l3,(short)l4,(short)l5,(short)l6,(short)l7};
}

// XOR swizzle within a 128-byte row (involution, both-sides applied)
__device__ __forceinline__ int swz128(int row, int cb) {
    return cb ^ ((row & 3) << 5) ^ (((row >> 2) & 1) << 4);
}

// ---------------- kernel 1: counted-vmcnt pipelined GEMM, W split in-register ----------------
// grid = 512 (B*T/128), 256 threads (4 waves). Depth-2, vmcnt(6), 2 blocks/CU.
// Proven optimum: depth-3 (r8), smaller blocks (r9), K-rotation (r5), and
// vmcnt(0)-drain (r3) all measured worse or neutral.
__global__ __launch_bounds__(256, 2) void lif_gemm_kernel(
    const float* __restrict__ seq, const float* __restrict__ Wg,
    const float* __restrict__ bias, const float* __restrict__ beta_raw,
    float* __restrict__ Cw, float* __restrict__ Mw)
{
    __shared__ __align__(16) unsigned char lds[49152];
    unsigned char* const A0 = lds;               // 16384: A fp32 [128][128B]
    unsigned char* const A1 = lds + 16384;       // 16384
    unsigned char* const W0 = lds + 32768;       // 8192:  W fp32 [64][128B]
    unsigned char* const W1 = lds + 40960;       // 8192

    const int tid  = threadIdx.x;
    const int wave = tid >> 6;
    const int lane = tid & 63;
    const int c = lane & 15;
    const int q = lane >> 4;
    const long row0 = (long)blockIdx.x * MBLK;

    // stage one k-chunk: 6 global_load_lds per thread (4 A + 2 W), all fp32
    auto stage = [&](unsigned char* Ab, unsigned char* Wb, int k0) {
        #pragma unroll
        for (int i = 0; i < 4; ++i) {
            int o16 = i * 256 + wave * 64 + lane;
            int row = o16 >> 3;                  // 0..127
            int cb  = (o16 & 7) << 4;
            int cbs = swz128(row, cb);
            gbl_void_t* src = (gbl_void_t*)(seq + (row0 + row) * D_ + k0 + (cbs >> 2));
            lds_void_t* dst = (lds_void_t*)(Ab + (i * 256 + wave * 64) * 16);
            __builtin_amdgcn_global_load_lds(src, dst, 16, 0, 0);
        }
        #pragma unroll
        for (int i = 0; i < 2; ++i) {
            int o16 = i * 256 + wave * 64 + lane;
            int row = o16 >> 3;                  // 0..63
            int cb  = (o16 & 7) << 4;
            int cbs = swz128(row, cb);
            gbl_void_t* src = (gbl_void_t*)(Wg + row * D_ + k0 + (cbs >> 2));
            lds_void_t* dst = (lds_void_t*)(Wb + (i * 256 + wave * 64) * 16);
            __builtin_amdgcn_global_load_lds(src, dst, 16, 0, 0);
        }
    };

    f32x4 acc[2][4] = {};

    auto compute = [&](const unsigned char* Ab, const unsigned char* Wb) {
        s16x8 ah[2], al[2], bh[4], bl[4];
        #pragma unroll
        for (int m = 0; m < 2; ++m) {
            int r = wave * 32 + m * 16 + c;
            float4 v0 = *(const float4*)(Ab + r * 128 + swz128(r, q * 32));
            float4 v1 = *(const float4*)(Ab + r * 128 + swz128(r, q * 32 + 16));
            split8(v0, v1, ah[m], al[m]);
        }
        #pragma unroll
        for (int n = 0; n < 4; ++n) {
            int r = n * 16 + c;
            float4 w0 = *(const float4*)(Wb + r * 128 + swz128(r, q * 32));
            float4 w1 = *(const float4*)(Wb + r * 128 + swz128(r, q * 32 + 16));
            split8(w0, w1, bh[n], bl[n]);
        }
        #pragma unroll
        for (int m = 0; m < 2; ++m)
            #pragma unroll
            for (int n = 0; n < 4; ++n)
                acc[m][n] = __builtin_amdgcn_mfma_f32_16x16x32_bf16(ah[m], bh[n], acc[m][n], 0, 0, 0);
        #pragma unroll
        for (int m = 0; m < 2; ++m)
            #pragma unroll
            for (int n = 0; n < 4; ++n)
                acc[m][n] = __builtin_amdgcn_mfma_f32_16x16x32_bf16(al[m], bh[n], acc[m][n], 0, 0, 0);
        #pragma unroll
        for (int m = 0; m < 2; ++m)
            #pragma unroll
            for (int n = 0; n < 4; ++n)
                acc[m][n] = __builtin_amdgcn_mfma_f32_16x16x32_bf16(ah[m], bl[n], acc[m][n], 0, 0, 0);
    };

    // ---- prologue: two stages in flight ----
    stage(A0, W0, 0);
    stage(A1, W1, BK);

    // ---- main loop: never drain vmcnt to 0 ----
    for (int t = 0; t < NCH - 2; t += 2) {
        asm volatile("s_waitcnt vmcnt(6)" ::: "memory");   // chunk t landed; t+1 in flight
        __builtin_amdgcn_s_barrier();
        compute(A0, W0);
        asm volatile("s_waitcnt lgkmcnt(0)" ::: "memory");
        __builtin_amdgcn_s_barrier();                       // all waves done reading buf0
        stage(A0, W0, (t + 2) * BK);

        asm volatile("s_waitcnt vmcnt(6)" ::: "memory");
        __builtin_amdgcn_s_barrier();
        compute(A1, W1);
        asm volatile("s_waitcnt lgkmcnt(0)" ::: "memory");
        __builtin_amdgcn_s_barrier();
        stage(A1, W1, (t + 3) * BK);
    }
    asm volatile("s_waitcnt vmcnt(6)" ::: "memory");
    __builtin_amdgcn_s_barrier();
    compute(A0, W0);
    asm volatile("s_waitcnt lgkmcnt(0)" ::: "memory");
    __builtin_amdgcn_s_barrier();
    asm volatile("s_waitcnt vmcnt(0)" ::: "memory");       // final drain
    __builtin_amdgcn_s_barrier();
    compute(A1, W1);

    // ---- epilogue: in-register scan compose, f(U)=min(beta*U + I_t, 1) ----
    // C/D layout: col = c (=> e = n*16+c), row = q*4 + r (=> t offset = m*16 + q*4 + r)
    float beta[4], A4[4], A8[4], bi[4];
    #pragma unroll
    for (int n = 0; n < 4; ++n) {
        beta[n] = 1.0f / (1.0f + __expf(-beta_raw[n * 16 + c]));
        float b2 = beta[n] * beta[n];
        A4[n] = b2 * b2;
        A8[n] = A4[n] * A4[n];
        bi[n] = bias[n * 16 + c];
    }

    float C[2][4], M[2][4];
    #pragma unroll
    for (int m = 0; m < 2; ++m)
        #pragma unroll
        for (int n = 0; n < 4; ++n) {
            float Cc = 0.0f, Mm = 3.0e38f;
            #pragma unroll
            for (int r = 0; r < 4; ++r) {
                float v = acc[m][n][r] + bi[n];
                Cc = fmaf(beta[n], Cc, v);
                Mm = fminf(fmaf(beta[n], Mm, v), THRESH);
            }
            C[m][n] = Cc; M[m][n] = Mm;
        }

    #pragma unroll
    for (int m = 0; m < 2; ++m)
        #pragma unroll
        for (int n = 0; n < 4; ++n) {
            {   // seglen 4 -> 8, A2 = beta^4
                float Cp = __shfl_xor(C[m][n], 16, 64);
                float Mp = __shfl_xor(M[m][n], 16, 64);
                bool sf = (lane & 16) == 0;
                float Cf = sf ? C[m][n] : Cp, Cs = sf ? Cp : C[m][n];
                float Mf = sf ? M[m][n] : Mp, Ms = sf ? Mp : M[m][n];
                C[m][n] = fmaf(A4[n], Cf, Cs);
                M[m][n] = fminf(fmaf(A4[n], Mf, Cs), Ms);
            }
            {   // seglen 8 -> 16, A2 = beta^8
                float Cp = __shfl_xor(C[m][n], 32, 64);
                float Mp = __shfl_xor(M[m][n], 32, 64);
                bool sf = (lane & 32) == 0;
                float Cf = sf ? C[m][n] : Cp, Cs = sf ? Cp : C[m][n];
                float Mf = sf ? M[m][n] : Mp, Ms = sf ? Mp : M[m][n];
                C[m][n] = fmaf(A8[n], Cf, Cs);
                M[m][n] = fminf(fmaf(A8[n], Mf, Cs), Ms);
            }
        }

    float Cm[4], Mm4[4];
    #pragma unroll
    for (int n = 0; n < 4; ++n) {
        float A16 = A8[n] * A8[n];
        Cm[n]  = fmaf(A16, C[0][n], C[1][n]);
        Mm4[n] = fminf(fmaf(A16, M[0][n], C[1][n]), M[1][n]);
    }

    float Co = (q == 0) ? Cm[0] : (q == 1) ? Cm[1] : (q == 2) ? Cm[2] : Cm[3];
    float Mo = (q == 0) ? Mm4[0] : (q == 1) ? Mm4[1] : (q == 2) ? Mm4[2] : Mm4[3];
    int sub = blockIdx.x * 4 + wave;
    Cw[sub * 64 + q * 16 + c] = Co;
    Mw[sub * 64 + q * 16 + c] = Mo;
}

// ---------------- kernel 2: combine 128 sub-chunks per batch + softmax ----------------
__global__ void lif_combine_kernel(const float* __restrict__ Cw, const float* __restrict__ Mw,
                                   const float* __restrict__ beta_raw, float* __restrict__ out)
{
    __shared__ float Cs[4][64], Ms[4][64];
    const int b = blockIdx.x;
    const int wv = threadIdx.x >> 6;
    const int e  = threadIdx.x & 63;

    float beta = 1.0f / (1.0f + __expf(-beta_raw[e]));
    float A32 = beta * beta;   // ^2
    A32 = A32 * A32;           // ^4
    A32 = A32 * A32;           // ^8
    A32 = A32 * A32;           // ^16
    A32 = A32 * A32;           // ^32

    const float* Cp = Cw + ((size_t)b * 128 + wv * 32) * 64 + e;
    const float* Mp = Mw + ((size_t)b * 128 + wv * 32) * 64 + e;
    float Cc = Cp[0], Mm = Mp[0];
    #pragma unroll 8
    for (int i = 1; i < 32; ++i) {
        float ci = Cp[i * 64], mi = Mp[i * 64];
        Mm = fminf(fmaf(A32, Mm, ci), mi);
        Cc = fmaf(A32, Cc, ci);
    }
    Cs[wv][e] = Cc; Ms[wv][e] = Mm;
    __syncthreads();

    if (threadIdx.x < 64) {
        float Ag = A32;            // -> beta^1024 via 5 squarings
        Ag = Ag * Ag; Ag = Ag * Ag; Ag = Ag * Ag; Ag = Ag * Ag; Ag = Ag * Ag;
        float C0 = Cs[0][e], M0 = Ms[0][e];
        #pragma unroll
        for (int g = 1; g < 4; ++g) {
            float ci = Cs[g][e], mi = Ms[g][e];
            M0 = fminf(fmaf(Ag, M0, ci), mi);
            C0 = fmaf(Ag, C0, ci);
        }
        float U = fminf(C0, M0);
        float m = U;
        #pragma unroll
        for (int off = 32; off; off >>= 1) m = fmaxf(m, __shfl_xor(m, off, 64));
        float ex = __expf(U - m);
        float s = ex;
        #pragma unroll
        for (int off = 32; off; off >>= 1) s += __shfl_xor(s, off, 64);
        out[b * 64 + e] = ex / s;
    }
}

extern "C" void kernel_launch(void* const* d_in, const int* in_sizes, int n_in,
                              void* d_out, int out_size, void* d_ws, size_t ws_size,
                              hipStream_t stream)
{
    const float* seq  = (const float*)d_in[0];
    const float* W    = (const float*)d_in[1];
    const float* bias = (const float*)d_in[2];
    const float* braw = (const float*)d_in[3];
    float* out = (float*)d_out;

    char* ws = (char*)d_ws;
    float* Cw = (float*)ws;                     // 2048*64*4 = 524288 B
    float* Mw = (float*)(ws + 524288);          // 524288 B

    lif_gemm_kernel<<<(B_ * T_) / MBLK, 256, 0, stream>>>(seq, W, bias, braw, Cw, Mw);
    lif_combine_kernel<<<B_, 256, 0, stream>>>(Cw, Mw, braw, out);
}